// Round 18
// baseline (548.820 us; speedup 1.0000x reference)
//
#include <hip/hip_runtime.h>
#include <hip/hip_bf16.h>
#include <hip/hip_cooperative_groups.h>
namespace cg = cooperative_groups;

#define BB 16
#define NN 64
#define PREVN 6
#define PREDN 30
#define HH 256
#define EE 4032              // NN*(NN-1)
#define EROWS (BB*EE)        // 64512
#define NROWS (BB*NN)        // 1024

typedef short short8 __attribute__((ext_vector_type(8)));
typedef float f32x4 __attribute__((ext_vector_type(4)));

// ---- f32 workspace layout (float element offsets) ----
enum : int {
  OFF_STATS_E = 0,       // [0:256]=sum [256:512]=sumsq
  OFF_STATS_M = 1024,    // [1024:1280]=sum [1280:1536]=sumsq
  OFF_XRS     = 2048,    // 262144 f32 slots = 524288 bf16: XR ++ XS
  F32_END     = 264192
};
// ---- bf16 area (element offsets within wb = (bf16*)(ws + F32_END)) ----
enum : size_t {
  BO_W1TE  = 0,          // 256*512 (n2e W1^T)
  BO_W2TE  = 131072,     // 256*256
  BO_W1TN  = 196608,     // 256*512 (e2n W1^T)
  BO_W2TN  = 327680,     // 256*256
  BO_WFT   = 393216,     // 256*512 (W_fuse^T)
  BO_WPT   = 524288,     // 64*256  (W_pred^T, zero-padded cols 60..63)
  BO_XG    = 540672,     // 1024*256 raw x (bf16)
  BO_NODES = 802816,     // 1024*512
  BO_M2    = 1327104,    // 1024*256
  BO_E2    = 2113536     // 64512*256
};

__device__ __forceinline__ float eluf(float v) { return v > 0.f ? v : __expf(v) - 1.f; }

__device__ __forceinline__ float xembed(const float* __restrict__ centers,
                                        const float* __restrict__ Wt,
                                        const float* __restrict__ bt,
                                        int rr, int col) {
  const float* c = centers + rr * 12;
  float acc = bt[col];
  #pragma unroll
  for (int t = 0; t < 5; ++t) {
    float dx = c[(t+1)*2 + 0] - c[t*2 + 0];
    float dy = c[(t+1)*2 + 1] - c[t*2 + 1];
    acc += dx * Wt[(2 + 2*t)*HH + col] + dy * Wt[(3 + 2*t)*HH + col];
  }
  return acc;
}

struct KArgs {
  const float *centers, *W_traj, *b_traj;
  const float *n2e_W1, *n2e_W2, *e2n_W1, *e2n_W2, *W_fuse, *W_pred;
  const float *n2e_b1, *n2e_b2, *n2e_g, *n2e_be;
  const float *e2n_b1, *e2n_b2, *e2n_g, *e2n_be;
  const float *b_fuse, *b_pred;
  float* stats;            // ws base: statsE @0, statsM @1024
  __hip_bfloat16 *w1te, *w2te, *w1tn, *w2tn, *wft, *wpt;
  __hip_bfloat16 *xg, *xrs, *e2, *nodes, *m2;
  float* out;
};

// ================= the whole pipeline, one cooperative kernel ==================
__global__ __launch_bounds__(256, 4) void k_all(KArgs a) {
  cg::grid_group grid = cg::this_grid();
  __shared__ alignas(16) char sm[36864];
  const int bid = blockIdx.x, tid = threadIdx.x;
  const int w = tid >> 6, lane = tid & 63;
  const int m16 = lane & 15, quad = lane >> 4;
  const int ko = quad * 8;

  // ======== P0: prep — transposes, wpt, zero stats, x-embed ========
  {
    if (bid < 128) {
      auto t = (float (*)[65])sm;                 // 64x65 f32 = 16.6 KB
      const float* W; __hip_bfloat16* WT; int K, lb;
      if (bid < 32)      { W = a.n2e_W1; WT = a.w1te; K = 512; lb = bid; }
      else if (bid < 48) { W = a.n2e_W2; WT = a.w2te; K = 256; lb = bid - 32; }
      else if (bid < 80) { W = a.e2n_W1; WT = a.w1tn; K = 512; lb = bid - 48; }
      else if (bid < 96) { W = a.e2n_W2; WT = a.w2tn; K = 256; lb = bid - 80; }
      else               { W = a.W_fuse; WT = a.wft;  K = 512; lb = bid - 96; }
      int KB = K / 64;
      int k0 = (lb % KB) * 64, n0 = (lb / KB) * 64;
      int tx = tid & 63, ty = tid >> 6;
      #pragma unroll
      for (int i = 0; i < 16; ++i)
        t[ty + i*4][tx] = W[(size_t)(k0 + ty + i*4) * 256 + n0 + tx];
      __syncthreads();
      #pragma unroll
      for (int i = 0; i < 16; ++i)
        WT[(size_t)(n0 + ty + i*4) * K + k0 + tx] = __float2bfloat16(t[tx][ty + i*4]);
    } else if (bid < 192) {
      int idx = (bid - 128) * 256 + tid;
      int c = idx >> 8, k = idx & 255;
      a.wpt[idx] = __float2bfloat16(c < 60 ? a.W_pred[k * 60 + c] : 0.f);
    } else if (bid < 200) {
      a.stats[(bid - 192) * 256 + tid] = 0.f;
    } else if (bid < 264) {
      int row0 = (bid - 200) * 16;
      #pragma unroll
      for (int r = 0; r < 16; ++r)
        a.xg[(size_t)(row0 + r)*256 + tid] =
            __float2bfloat16(xembed(a.centers, a.W_traj, a.b_traj, row0 + r, tid));
    }
  }
  grid.sync();

  // ======== P1: XR/XS = xg @ W1_{top,bot} — 512 wave-units ========
  {
    const int gw = bid * 4 + w;
    if (gw < 512) {
      const int rt = gw >> 3, s = gw & 7;
      const int half = s >> 2, j0 = (s & 3) * 64;
      const int row0 = rt * 16;
      __hip_bfloat16* dst = a.xrs + (size_t)half * 262144;
      f32x4 acc[4];
      #pragma unroll
      for (int jt = 0; jt < 4; ++jt) {
        float bv = half ? 0.f : a.n2e_b1[j0 + jt*16 + m16];
        acc[jt] = (f32x4){bv, bv, bv, bv};
      }
      #pragma unroll
      for (int ks = 0; ks < 8; ++ks) {
        short8 af = *reinterpret_cast<const short8*>(
            a.xg + (size_t)(row0 + m16)*256 + ks*32 + ko);
        short8 bf[4];
        #pragma unroll
        for (int jt = 0; jt < 4; ++jt)
          bf[jt] = *reinterpret_cast<const short8*>(
              a.w1te + (size_t)(j0 + jt*16 + m16)*512 + half*256 + ks*32 + ko);
        #pragma unroll
        for (int jt = 0; jt < 4; ++jt)
          acc[jt] = __builtin_amdgcn_mfma_f32_16x16x32_bf16(af, bf[jt], acc[jt], 0, 0, 0);
      }
      #pragma unroll
      for (int jt = 0; jt < 4; ++jt)
        #pragma unroll
        for (int r = 0; r < 4; ++r)
          dst[(size_t)(row0 + quad*4 + r)*256 + j0 + jt*16 + m16] =
              __float2bfloat16(acc[jt][r]);
    }
  }
  grid.sync();

  // ======== P2: edge MLP (2 tiles per block) ========
  {
    auto h1s = (__hip_bfloat16 (*)[264])sm;       // 33792 B
    float* sst0 = (float*)(sm + 33792);           // 1024
    float* sst1 = (float*)(sm + 34816);           // 1024
    int* sd64 = (int*)(sm + 35840);               // 256
    int* rcf  = (int*)(sm + 36096);               // 256
    const int colw = w * 64;
    for (int t = bid; t < 1008; t += 512) {
      const int bb = t / 63, lb = t - bb*63;
      const int row0 = t * 64;
      const int n0 = (lb * 64) / 63;
      if (tid < 64) {
        int e = lb*64 + tid;
        int rc = e / 63; int jj = e - rc*63;
        sd64[tid] = jj + (jj >= rc ? 1 : 0);
        rcf[tid]  = rc - n0;
      }
      sst0[tid] = 0.f;
      sst1[tid] = 0.f;
      __syncthreads();

      {  // h1 = elu(XR[rc] + XS[sd]) from global (L2-hot)
        const int ty = tid >> 7;
        const int c2 = (tid & 127) * 2;
        const __hip_bfloat16* xrb = a.xrs + (size_t)(bb*64 + n0)*256 + c2;
        const __hip_bfloat16* xsb = a.xrs + 262144 + (size_t)bb*64*256 + c2;
        #pragma unroll 4
        for (int r2 = 0; r2 < 32; ++r2) {
          int r = ty*32 + r2;
          __hip_bfloat162 xa = *reinterpret_cast<const __hip_bfloat162*>(
              xrb + (size_t)rcf[r]*256);
          __hip_bfloat162 xs2 = *reinterpret_cast<const __hip_bfloat162*>(
              xsb + (size_t)sd64[r]*256);
          __hip_bfloat162 o;
          o.x = __float2bfloat16(eluf(__bfloat162float(xa.x) + __bfloat162float(xs2.x)));
          o.y = __float2bfloat16(eluf(__bfloat162float(xa.y) + __bfloat162float(xs2.y)));
          *reinterpret_cast<__hip_bfloat162*>(&h1s[r][c2]) = o;
        }
      }
      __syncthreads();

      f32x4 acc2[4][4];
      #pragma unroll
      for (int jt = 0; jt < 4; ++jt) {
        float bv = a.n2e_b2[colw + jt*16 + m16];
        #pragma unroll
        for (int mt = 0; mt < 4; ++mt) acc2[mt][jt] = (f32x4){bv, bv, bv, bv};
      }
      #pragma unroll
      for (int kt = 0; kt < 4; ++kt) {
        #pragma unroll
        for (int ks = 0; ks < 2; ++ks) {
          const int k0 = kt*64 + ks*32 + ko;
          short8 af[4], bf[4];
          #pragma unroll
          for (int jt = 0; jt < 4; ++jt)
            bf[jt] = *reinterpret_cast<const short8*>(
                a.w2te + (size_t)(colw + jt*16 + m16)*256 + k0);
          #pragma unroll
          for (int mt = 0; mt < 4; ++mt)
            af[mt] = *(const short8*)((const char*)h1s +
                         (size_t)(mt*16 + m16)*528 + k0*2);
          #pragma unroll
          for (int mt = 0; mt < 4; ++mt)
            #pragma unroll
            for (int jt = 0; jt < 4; ++jt)
              acc2[mt][jt] = __builtin_amdgcn_mfma_f32_16x16x32_bf16(af[mt], bf[jt],
                                                                     acc2[mt][jt], 0, 0, 0);
        }
      }
      __syncthreads();

      #pragma unroll
      for (int jt = 0; jt < 4; ++jt) {
        float ps = 0.f, pq = 0.f;
        #pragma unroll
        for (int mt = 0; mt < 4; ++mt)
          #pragma unroll
          for (int r = 0; r < 4; ++r) {
            float hv = eluf(acc2[mt][jt][r]);
            h1s[mt*16 + quad*4 + r][colw + jt*16 + m16] = __float2bfloat16(hv);
            ps += hv; pq += hv * hv;
          }
        atomicAdd(&sst0[colw + jt*16 + m16], ps);
        atomicAdd(&sst1[colw + jt*16 + m16], pq);
      }
      __syncthreads();

      atomicAdd(&a.stats[tid], sst0[tid]);
      atomicAdd(&a.stats[256 + tid], sst1[tid]);
      #pragma unroll
      for (int i = 0; i < 8; ++i) {
        int u = i*256 + tid;
        int r = u >> 5, c = (u & 31) * 8;
        *reinterpret_cast<uint4*>(a.e2 + (size_t)(row0 + r)*HH + c) =
            *reinterpret_cast<const uint4*>(&h1s[r][c]);
      }
      __syncthreads();   // sst/h1s reuse next iteration
    }
  }
  grid.sync();

  // ======== P3: BN-fused edge->node aggregation — 2048 units, 4 per block ======
  {
    auto red = (float (*)[256])sm;                // 8 KB
    const int c8 = (tid & 31) * 8;
    const int rg = tid >> 5;                      // 0..7
    for (int u = bid; u < 2048; u += 512) {
      const int bn = u >> 1, half = u & 1;
      const int b = bn >> 6, n = bn & 63;
      const __hip_bfloat16* base = a.e2 + (size_t)b * EE * HH;
      float s[8] = {0.f,0.f,0.f,0.f,0.f,0.f,0.f,0.f};
      for (int j = rg; j < 63; j += 8) {
        const __hip_bfloat16* rp;
        if (half == 0) {
          rp = base + (size_t)(n*63 + j)*HH;
        } else {
          int i = j + (j >= n ? 1 : 0);
          int e = i*63 + n - (n > i ? 1 : 0);
          rp = base + (size_t)e*HH;
        }
        union { uint4 u4; __hip_bfloat16 h[8]; } v;
        v.u4 = *reinterpret_cast<const uint4*>(rp + c8);
        #pragma unroll
        for (int jj = 0; jj < 8; ++jj) s[jj] += __bfloat162float(v.h[jj]);
      }
      #pragma unroll
      for (int jj = 0; jj < 8; jj += 4)
        *reinterpret_cast<float4*>(&red[rg][c8 + jj]) =
            (float4){s[jj], s[jj+1], s[jj+2], s[jj+3]};
      __syncthreads();
      {
        float S = 0.f;
        #pragma unroll
        for (int r = 0; r < 8; ++r) S += red[r][tid];
        const float inv = 1.f / (float)EROWS;
        float mean = a.stats[tid] * inv;
        float var  = fmaxf(a.stats[256 + tid] * inv - mean*mean, 0.f);
        float aa = a.n2e_g[tid] * rsqrtf(var + 1e-5f);
        float c0 = a.n2e_be[tid] - mean * aa;
        a.nodes[(size_t)bn*512 + half*256 + tid] =
            __float2bfloat16(aa * S * (1.f/63.f) + c0);
      }
      __syncthreads();
    }
  }
  grid.sync();

  // ======== P4: node MLP (block-local L1+L2+stats) — 64 blocks ========
  if (bid < 64) {
    auto h1 = (__hip_bfloat16 (*)[264])sm;        // 8448 B
    float* s0 = (float*)(sm + 8448);              // 1024
    float* s1 = (float*)(sm + 9472);              // 1024
    const int row0 = bid * 16;
    const int j0 = w * 64;
    s0[tid] = 0.f;
    s1[tid] = 0.f;

    f32x4 acc[4];
    #pragma unroll
    for (int jt = 0; jt < 4; ++jt) {
      float bv = a.e2n_b1[j0 + jt*16 + m16];
      acc[jt] = (f32x4){bv, bv, bv, bv};
    }
    #pragma unroll
    for (int ks = 0; ks < 16; ++ks) {
      short8 af = *reinterpret_cast<const short8*>(
          a.nodes + (size_t)(row0 + m16)*512 + ks*32 + ko);
      short8 bf[4];
      #pragma unroll
      for (int jt = 0; jt < 4; ++jt)
        bf[jt] = *reinterpret_cast<const short8*>(
            a.w1tn + (size_t)(j0 + jt*16 + m16)*512 + ks*32 + ko);
      #pragma unroll
      for (int jt = 0; jt < 4; ++jt)
        acc[jt] = __builtin_amdgcn_mfma_f32_16x16x32_bf16(af, bf[jt], acc[jt], 0, 0, 0);
    }
    #pragma unroll
    for (int jt = 0; jt < 4; ++jt)
      #pragma unroll
      for (int r = 0; r < 4; ++r)
        h1[quad*4 + r][j0 + jt*16 + m16] = __float2bfloat16(eluf(acc[jt][r]));
    __syncthreads();

    f32x4 acc2[4];
    #pragma unroll
    for (int jt = 0; jt < 4; ++jt) {
      float bv = a.e2n_b2[j0 + jt*16 + m16];
      acc2[jt] = (f32x4){bv, bv, bv, bv};
    }
    #pragma unroll
    for (int ks = 0; ks < 8; ++ks) {
      short8 af = *(const short8*)((const char*)h1 + (size_t)m16*528 + (ks*32 + ko)*2);
      short8 bf[4];
      #pragma unroll
      for (int jt = 0; jt < 4; ++jt)
        bf[jt] = *reinterpret_cast<const short8*>(
            a.w2tn + (size_t)(j0 + jt*16 + m16)*256 + ks*32 + ko);
      #pragma unroll
      for (int jt = 0; jt < 4; ++jt)
        acc2[jt] = __builtin_amdgcn_mfma_f32_16x16x32_bf16(af, bf[jt], acc2[jt], 0, 0, 0);
    }
    #pragma unroll
    for (int jt = 0; jt < 4; ++jt) {
      float ps = 0.f, pq = 0.f;
      #pragma unroll
      for (int r = 0; r < 4; ++r) {
        float hv = eluf(acc2[jt][r]);
        a.m2[(size_t)(row0 + quad*4 + r)*256 + j0 + jt*16 + m16] = __float2bfloat16(hv);
        ps += hv; pq += hv * hv;
      }
      atomicAdd(&s0[j0 + jt*16 + m16], ps);
      atomicAdd(&s1[j0 + jt*16 + m16], pq);
    }
    __syncthreads();
    atomicAdd(&a.stats[1024 + tid], s0[tid]);
    atomicAdd(&a.stats[1280 + tid], s1[tid]);
  }
  grid.sync();

  // ======== P5: head (fuse + pred + cumsum, block-local) — 64 blocks ========
  if (bid < 64) {
    float* bnA = (float*)sm;                      // 1024
    float* bnC = (float*)(sm + 1024);             // 1024
    auto fl = (__hip_bfloat16 (*)[264])(sm + 2048);   // 8448
    auto rl = (float (*)[68])(sm + 10496);        // 4352
    const int row0 = bid * 16;
    const int j0 = w * 64;

    {
      const float inv = 1.f / (float)NROWS;
      float mean = a.stats[1024 + tid] * inv;
      float var  = fmaxf(a.stats[1280 + tid] * inv - mean*mean, 0.f);
      float am = a.e2n_g[tid] * rsqrtf(var + 1e-5f);
      bnA[tid] = am;
      bnC[tid] = a.e2n_be[tid] - mean * am;
    }
    __syncthreads();

    // fuse: 16x512 @ 512x256 (wave w covers cols j0..j0+63)
    f32x4 acc[4];
    #pragma unroll
    for (int jt = 0; jt < 4; ++jt) {
      float bv = a.b_fuse[j0 + jt*16 + m16];
      acc[jt] = (f32x4){bv, bv, bv, bv};
    }
    #pragma unroll
    for (int ks = 0; ks < 16; ++ks) {
      short8 af;
      if (ks < 8) {
        af = *reinterpret_cast<const short8*>(
            a.xg + (size_t)(row0 + m16)*256 + ks*32 + ko);
      } else {
        int k0 = (ks - 8)*32 + ko;
        union { uint4 u4; __hip_bfloat16 h[8]; } v;
        v.u4 = *reinterpret_cast<const uint4*>(a.m2 + (size_t)(row0 + m16)*256 + k0);
        union { short8 s8; __hip_bfloat16 h[8]; } o;
        #pragma unroll
        for (int j = 0; j < 8; ++j)
          o.h[j] = __float2bfloat16(bnA[k0+j] * __bfloat162float(v.h[j]) + bnC[k0+j]);
        af = o.s8;
      }
      short8 bf[4];
      #pragma unroll
      for (int jt = 0; jt < 4; ++jt)
        bf[jt] = *reinterpret_cast<const short8*>(
            a.wft + (size_t)(j0 + jt*16 + m16)*512 + ks*32 + ko);
      #pragma unroll
      for (int jt = 0; jt < 4; ++jt)
        acc[jt] = __builtin_amdgcn_mfma_f32_16x16x32_bf16(af, bf[jt], acc[jt], 0, 0, 0);
    }
    #pragma unroll
    for (int jt = 0; jt < 4; ++jt)
      #pragma unroll
      for (int r = 0; r < 4; ++r)
        fl[quad*4 + r][j0 + jt*16 + m16] = __float2bfloat16(acc[jt][r]);  // no act
    __syncthreads();

    if (w == 0) {
      f32x4 acc2[4];
      #pragma unroll
      for (int jt = 0; jt < 4; ++jt) {
        int c = jt*16 + m16;
        float bv = (c < 60) ? a.b_pred[c] : 0.f;
        acc2[jt] = (f32x4){bv, bv, bv, bv};
      }
      #pragma unroll
      for (int ks = 0; ks < 8; ++ks) {
        short8 af = *(const short8*)((const char*)fl + (size_t)m16*528 + (ks*32 + ko)*2);
        short8 bf[4];
        #pragma unroll
        for (int jt = 0; jt < 4; ++jt)
          bf[jt] = *reinterpret_cast<const short8*>(
              a.wpt + (size_t)(jt*16 + m16)*256 + ks*32 + ko);
        #pragma unroll
        for (int jt = 0; jt < 4; ++jt)
          acc2[jt] = __builtin_amdgcn_mfma_f32_16x16x32_bf16(af, bf[jt], acc2[jt], 0, 0, 0);
      }
      #pragma unroll
      for (int jt = 0; jt < 4; ++jt) {
        int c = jt*16 + m16;
        #pragma unroll
        for (int r = 0; r < 4; ++r) {
          int lr = quad*4 + r;
          rl[lr][c] = acc2[jt][r];
          if (c < 60) a.out[(size_t)(row0 + lr)*60 + c] = acc2[jt][r];
        }
      }
    }
    __syncthreads();

    if (tid < 32) {
      int lr = tid >> 1, xy = tid & 1;
      int grow = row0 + lr;
      float run = a.centers[(size_t)(grow*PREVN + 5)*2 + xy];
      #pragma unroll
      for (int p = 0; p < PREDN; ++p) {
        run += rl[lr][2*p + xy];
        a.out[61440 + (size_t)grow*60 + 2*p + xy] = run;
      }
    }
  }
}

extern "C" void kernel_launch(void* const* d_in, const int* in_sizes, int n_in,
                              void* d_out, int out_size, void* d_ws, size_t ws_size,
                              hipStream_t stream) {
  float* ws = (float*)d_ws;
  __hip_bfloat16* wb = (__hip_bfloat16*)(ws + F32_END);

  KArgs ka;
  ka.centers = (const float*)d_in[0];
  ka.W_traj  = (const float*)d_in[3];
  ka.b_traj  = (const float*)d_in[4];
  ka.n2e_W1  = (const float*)d_in[5];
  ka.n2e_b1  = (const float*)d_in[6];
  ka.n2e_W2  = (const float*)d_in[7];
  ka.n2e_b2  = (const float*)d_in[8];
  ka.n2e_g   = (const float*)d_in[9];
  ka.n2e_be  = (const float*)d_in[10];
  ka.e2n_W1  = (const float*)d_in[11];
  ka.e2n_b1  = (const float*)d_in[12];
  ka.e2n_W2  = (const float*)d_in[13];
  ka.e2n_b2  = (const float*)d_in[14];
  ka.e2n_g   = (const float*)d_in[15];
  ka.e2n_be  = (const float*)d_in[16];
  ka.W_fuse  = (const float*)d_in[17];
  ka.b_fuse  = (const float*)d_in[18];
  ka.W_pred  = (const float*)d_in[19];
  ka.b_pred  = (const float*)d_in[20];
  ka.stats = ws;
  ka.w1te = wb + BO_W1TE; ka.w2te = wb + BO_W2TE;
  ka.w1tn = wb + BO_W1TN; ka.w2tn = wb + BO_W2TN;
  ka.wft  = wb + BO_WFT;  ka.wpt  = wb + BO_WPT;
  ka.xg   = wb + BO_XG;
  ka.xrs  = (__hip_bfloat16*)(ws + OFF_XRS);
  ka.e2   = wb + BO_E2;
  ka.nodes = wb + BO_NODES;
  ka.m2   = wb + BO_M2;
  ka.out  = (float*)d_out;

  void* params[] = { &ka };
  hipLaunchCooperativeKernel(reinterpret_cast<void*>(k_all),
                             dim3(512), dim3(256), params, 0, stream);
}